// Round 17
// baseline (70.792 us; speedup 1.0000x reference)
//
#include <hip/hip_runtime.h>

// IoU assigner: N anchors x M gts (3D, 6 coords). Outputs (concatenated, f32):
//   out[0:N]   labels (-1 ignore, 0 neg, gt_label pos)
//   out[N:7N]  assigned boxes (gt box if pos, else -1.0)
//
// Bit-exact vs numpy f32: __f*_rn intrinsics (no FMA contraction), op order
// mirrors the jnp reference; argmax ties: first index (strict > scan; the
// cross-chunk merge encodes (iou_bits<<32)|~g so max picks smallest g).
//
// Round-17: R16 shape (SGPR-delivered gt operands, 3 dispatches, clean
// codegen) with 8 anchors/lane (stride H8=(N+7)/8). R12-R16 converged at
// 43-47us with VALUBusy 80-86% across 5 different inner loops -> the loop
// is near VALU/issue-bound; the last untested lever is per-(wave,gt)
// overhead (loop ctl, s_loads, branch scaffolding), which halves with 8
// chains/wave. Null result (>=42us) => declare roofline on R16.
// UNFUSED override + memset (fusion provably spills: R3-R8 ticket, R15 coop).
//
// ws layout: [0,1024) slots[128] u64.

#define MMAX 128

// ---- uniform gt operand load (SMEM s_load via readfirstlane address) ----
#define LOAD_GT(J)                                                             \
    const float q##J##x0 = gq[(J)*6+0], q##J##y0 = gq[(J)*6+1],                \
                q##J##z0 = gq[(J)*6+2], q##J##x1 = gq[(J)*6+3],                \
                q##J##y1 = gq[(J)*6+4], q##J##z1 = gq[(J)*6+5];                \
    const float q##J##ar = __fmul_rn(__fmul_rn(__fsub_rn(q##J##x1, q##J##x0),  \
                            __fsub_rn(q##J##y1, q##J##y0)),                    \
                            __fsub_rn(q##J##z1, q##J##z0));

// ---- one (gt J, chain K) IoU step, all operands register/SGPR resident ----
#define IOU_SK(J, K)                                                           \
    {                                                                          \
        float cx = fmaxf(__fsub_rn(fminf(c##K##x1, q##J##x1),                  \
                                   fmaxf(c##K##x0, q##J##x0)), 0.f);           \
        float cy = fmaxf(__fsub_rn(fminf(c##K##y1, q##J##y1),                  \
                                   fmaxf(c##K##y0, q##J##y0)), 0.f);           \
        float cz = fmaxf(__fsub_rn(fminf(c##K##z1, q##J##z1),                  \
                                   fmaxf(c##K##z0, q##J##z0)), 0.f);           \
        float inter = __fmul_rn(__fmul_rn(cx, cy), cz);                        \
        if (inter > 0.f) { /* ~0.3% of pairs */                                \
            float den = __fadd_rn(__fsub_rn(__fadd_rn(ar##K, q##J##ar), inter),\
                                  1e-7f);                                      \
            float iou = __fdiv_rn(inter, den);                                 \
            if (iou > bst##K) { bst##K = iou; idx##K = u + (J); }              \
            if (iou >= 0.3f) {                                                 \
                unsigned long long enc =                                       \
                    ((unsigned long long)__float_as_uint(iou) << 32) |         \
                    (unsigned long long)e##K;                                  \
                atomicMax(&lsl[u + (J)], enc);                                 \
            }                                                                  \
        }                                                                      \
    }

#define IOU_GT8(J)                                                             \
    IOU_SK(J,0) IOU_SK(J,1) IOU_SK(J,2) IOU_SK(J,3)                            \
    IOU_SK(J,4) IOU_SK(J,5) IOU_SK(J,6) IOU_SK(J,7)

#define DECL_CHAIN(K)                                                          \
    float c##K##x0 = 0.f, c##K##y0 = 0.f, c##K##z0 = 0.f,                      \
          c##K##x1 = 0.f, c##K##y1 = 0.f, c##K##z1 = 0.f;

#define LOAD_CHAIN(K)                                                          \
    if (v##K) { const float* p = bx + (size_t)(base + (K) * H8) * 6;           \
        c##K##x0 = p[0]; c##K##y0 = p[1]; c##K##z0 = p[2];                     \
        c##K##x1 = p[3]; c##K##y1 = p[4]; c##K##z1 = p[5]; }

#define AREA_CHAIN(K)                                                          \
    const float ar##K = __fmul_rn(__fmul_rn(__fsub_rn(c##K##x1, c##K##x0),     \
                         __fsub_rn(c##K##y1, c##K##y0)),                       \
                         __fsub_rn(c##K##z1, c##K##z0));

#define MERGE_CHAIN(K)                                                         \
    if (v##K) atomicMax(&asl[(K) * 64 + lane],                                 \
        ((unsigned long long)__float_as_uint(bst##K) << 32) |                  \
        (unsigned long long)(0xFFFFFFFFu - (unsigned)idx##K));

// ================= fast path: M == 128, 8 chains/lane =================
__global__ __launch_bounds__(256) void iou_main8(
    const float* __restrict__ bx, const float* __restrict__ gt,
    const int* __restrict__ gl,
    float* __restrict__ out_lab, float* __restrict__ out_bb,
    unsigned long long* __restrict__ slots,
    int N)
{
    const int M = MMAX;
    const int tid  = threadIdx.x;
    const int lane = tid & 63;
    const int wv   = tid >> 6;

    __shared__ float4 gb4[MMAX * 2];  // [2g]={x0,y0,z0,x1} [2g+1]={y1,z1,area,label}
    __shared__ unsigned long long lsl[MMAX];   // per-gt column max
    __shared__ unsigned long long asl[512];    // per-anchor (best,arg) merge
    if (tid < M) {
        const float* gp = gt + (size_t)tid * 6;
        float x0 = gp[0], y0 = gp[1], z0 = gp[2];
        float x1 = gp[3], y1 = gp[4], z1 = gp[5];
        float area = __fmul_rn(__fmul_rn(__fsub_rn(x1, x0), __fsub_rn(y1, y0)),
                               __fsub_rn(z1, z0));
        gb4[2 * tid]     = make_float4(x0, y0, z0, x1);
        gb4[2 * tid + 1] = make_float4(y1, z1, area, (float)gl[tid]);
    }
    if (tid < MMAX) lsl[tid] = 0ULL;
    asl[tid] = 0ULL; asl[tid + 256] = 0ULL;
    __syncthreads();

    // ---- eight anchors per LANE at stride H8; all 4 waves share them ----
    const int H8 = (N + 7) >> 3;
    const int base = blockIdx.x * 64 + lane;
    const bool v0 = (base < H8);
    const bool v1 = v0 && (base + 1 * H8 < N);
    const bool v2 = v0 && (base + 2 * H8 < N);
    const bool v3 = v0 && (base + 3 * H8 < N);
    const bool v4 = v0 && (base + 4 * H8 < N);
    const bool v5 = v0 && (base + 5 * H8 < N);
    const bool v6 = v0 && (base + 6 * H8 < N);
    const bool v7 = v0 && (base + 7 * H8 < N);

    DECL_CHAIN(0) DECL_CHAIN(1) DECL_CHAIN(2) DECL_CHAIN(3)
    DECL_CHAIN(4) DECL_CHAIN(5) DECL_CHAIN(6) DECL_CHAIN(7)
    LOAD_CHAIN(0) LOAD_CHAIN(1) LOAD_CHAIN(2) LOAD_CHAIN(3)
    LOAD_CHAIN(4) LOAD_CHAIN(5) LOAD_CHAIN(6) LOAD_CHAIN(7)
    AREA_CHAIN(0) AREA_CHAIN(1) AREA_CHAIN(2) AREA_CHAIN(3)
    AREA_CHAIN(4) AREA_CHAIN(5) AREA_CHAIN(6) AREA_CHAIN(7)

    const unsigned e0 = 0xFFFFFFFFu - (unsigned)(base + 0 * H8);
    const unsigned e1 = 0xFFFFFFFFu - (unsigned)(base + 1 * H8);
    const unsigned e2 = 0xFFFFFFFFu - (unsigned)(base + 2 * H8);
    const unsigned e3 = 0xFFFFFFFFu - (unsigned)(base + 3 * H8);
    const unsigned e4 = 0xFFFFFFFFu - (unsigned)(base + 4 * H8);
    const unsigned e5 = 0xFFFFFFFFu - (unsigned)(base + 5 * H8);
    const unsigned e6 = 0xFFFFFFFFu - (unsigned)(base + 6 * H8);
    const unsigned e7 = 0xFFFFFFFFu - (unsigned)(base + 7 * H8);

    const int g0w = wv * 32;
    float bst0 = 0.f, bst1 = 0.f, bst2 = 0.f, bst3 = 0.f,
          bst4 = 0.f, bst5 = 0.f, bst6 = 0.f, bst7 = 0.f;
    int   idx0 = g0w, idx1 = g0w, idx2 = g0w, idx3 = g0w,
          idx4 = g0w, idx5 = g0w, idx6 = g0w, idx7 = g0w;

    // ---- 4 sub-chunks of 8 gts: 48 uniform floats -> SGPRs, one drain,
    //      then 64 memory-free IoU instances ----
    for (int cs = 0; cs < 32; cs += 8) {
        const int u = __builtin_amdgcn_readfirstlane(g0w + cs);
        const float* gq = gt + (size_t)u * 6;
        LOAD_GT(0) LOAD_GT(1) LOAD_GT(2) LOAD_GT(3)
        LOAD_GT(4) LOAD_GT(5) LOAD_GT(6) LOAD_GT(7)
        IOU_GT8(0) IOU_GT8(1) IOU_GT8(2) IOU_GT8(3)
        IOU_GT8(4) IOU_GT8(5) IOU_GT8(6) IOU_GT8(7)
    }

    MERGE_CHAIN(0) MERGE_CHAIN(1) MERGE_CHAIN(2) MERGE_CHAIN(3)
    MERGE_CHAIN(4) MERGE_CHAIN(5) MERGE_CHAIN(6) MERGE_CHAIN(7)
    __syncthreads();

    // ---- flush per-gt maxima to global slots ----
    if (tid < M) {
        unsigned long long v = lsl[tid];
        if (v) atomicMax(&slots[tid], v);
    }

    // ---- epilogue: 512 anchor slots, 2 per thread ----
    for (int s = tid; s < 512; s += 256) {
        const int k = s >> 6, l = s & 63;
        const int sb = blockIdx.x * 64 + l;
        const int anchor = sb + k * H8;
        if (sb < H8 && anchor < N) {
            const unsigned long long v = asl[s];
            const float best = __uint_as_float((unsigned)(v >> 32));
            const int garg = (int)(0xFFFFFFFFu - (unsigned)(v & 0xFFFFFFFFu));
            const float* gbf = (const float*)gb4;   // [8g+0..5]=box +6=area +7=label
            float lab;
            if (best >= 0.7f) lab = gbf[8 * garg + 7];
            else              lab = (best < 0.3f) ? 0.f : -1.f;
            out_lab[anchor] = lab;
            float* ob = out_bb + (size_t)anchor * 6;
            if (best >= 0.7f) {
                ob[0] = gbf[8*garg+0]; ob[1] = gbf[8*garg+1]; ob[2] = gbf[8*garg+2];
                ob[3] = gbf[8*garg+3]; ob[4] = gbf[8*garg+4]; ob[5] = gbf[8*garg+5];
            } else {
                ob[0] = -1.f; ob[1] = -1.f; ob[2] = -1.f;
                ob[3] = -1.f; ob[4] = -1.f; ob[5] = -1.f;
            }
        }
    }
}

// ================= generic path (runtime M): R13 kernel =================
#define IOU_ONE(GLO, GHI, G, X0, Y0, Z0, X1, Y1, Z1, AR, BEST, ARG, ENC)       \
    {                                                                          \
        float cx = fmaxf(__fsub_rn(fminf(X1, GLO.w), fmaxf(X0, GLO.x)), 0.f);  \
        float cy = fmaxf(__fsub_rn(fminf(Y1, GHI.x), fmaxf(Y0, GLO.y)), 0.f);  \
        float cz = fmaxf(__fsub_rn(fminf(Z1, GHI.y), fmaxf(Z0, GLO.z)), 0.f);  \
        float inter = __fmul_rn(__fmul_rn(cx, cy), cz);                        \
        if (inter > 0.f) {                                                     \
            float den = __fadd_rn(__fsub_rn(__fadd_rn(AR, GHI.z), inter), 1e-7f);\
            float iou = __fdiv_rn(inter, den);                                 \
            if (iou > BEST) { BEST = iou; ARG = (G); }                         \
            if (iou >= 0.3f) {                                                 \
                unsigned long long enc =                                       \
                    ((unsigned long long)__float_as_uint(iou) << 32) |         \
                    (unsigned long long)(ENC);                                 \
                atomicMax(&lsl[(G)], enc);                                     \
            }                                                                  \
        }                                                                      \
    }

#define IOU_G(GLO, GHI, G)                                                     \
    IOU_ONE(GLO, GHI, G, ax0, ay0, az0, ax1, ay1, az1, a1a, bestA, argA, encA) \
    IOU_ONE(GLO, GHI, G, bx0, by0, bz0, bx1, by1, bz1, a1b, bestB, argB, encB) \
    IOU_ONE(GLO, GHI, G, cx0, cy0, cz0, cx1, cy1, cz1, a1c, bestC, argC, encC) \
    IOU_ONE(GLO, GHI, G, dx0, dy0, dz0, dx1, dy1, dz1, a1d, bestD, argD, encD)

__global__ __launch_bounds__(256) void iou_main_generic(
    const float* __restrict__ bx, const float* __restrict__ gt,
    const int* __restrict__ gl,
    float* __restrict__ out_lab, float* __restrict__ out_bb,
    unsigned long long* __restrict__ slots,
    int N, int M)
{
    const int tid  = threadIdx.x;
    const int lane = tid & 63;
    const int wv   = tid >> 6;

    __shared__ float4 gb4[MMAX * 2];
    __shared__ unsigned long long lsl[MMAX];
    __shared__ unsigned long long asl[256];
    if (tid < M) {
        const float* gp = gt + (size_t)tid * 6;
        float x0 = gp[0], y0 = gp[1], z0 = gp[2];
        float x1 = gp[3], y1 = gp[4], z1 = gp[5];
        float area = __fmul_rn(__fmul_rn(__fsub_rn(x1, x0), __fsub_rn(y1, y0)),
                               __fsub_rn(z1, z0));
        gb4[2 * tid]     = make_float4(x0, y0, z0, x1);
        gb4[2 * tid + 1] = make_float4(y1, z1, area, (float)gl[tid]);
    }
    if (tid < MMAX) lsl[tid] = 0ULL;
    asl[tid] = 0ULL;
    __syncthreads();

    const int H = (N + 3) >> 2;
    const int base = blockIdx.x * 64 + lane;
    const int a = base, b = base + H, c = base + 2 * H, d = base + 3 * H;
    const bool va = (base < H);
    const bool vb = va && (b < N);
    const bool vc = va && (c < N);
    const bool vd = va && (d < N);

    float ax0 = 0.f, ay0 = 0.f, az0 = 0.f, ax1 = 0.f, ay1 = 0.f, az1 = 0.f;
    if (va) { const float* p = bx + (size_t)a * 6;
        ax0 = p[0]; ay0 = p[1]; az0 = p[2]; ax1 = p[3]; ay1 = p[4]; az1 = p[5]; }
    float bx0 = 0.f, by0 = 0.f, bz0 = 0.f, bx1 = 0.f, by1 = 0.f, bz1 = 0.f;
    if (vb) { const float* p = bx + (size_t)b * 6;
        bx0 = p[0]; by0 = p[1]; bz0 = p[2]; bx1 = p[3]; by1 = p[4]; bz1 = p[5]; }
    float cx0 = 0.f, cy0 = 0.f, cz0 = 0.f, cx1 = 0.f, cy1 = 0.f, cz1 = 0.f;
    if (vc) { const float* p = bx + (size_t)c * 6;
        cx0 = p[0]; cy0 = p[1]; cz0 = p[2]; cx1 = p[3]; cy1 = p[4]; cz1 = p[5]; }
    float dx0 = 0.f, dy0 = 0.f, dz0 = 0.f, dx1 = 0.f, dy1 = 0.f, dz1 = 0.f;
    if (vd) { const float* p = bx + (size_t)d * 6;
        dx0 = p[0]; dy0 = p[1]; dz0 = p[2]; dx1 = p[3]; dy1 = p[4]; dz1 = p[5]; }

    const float a1a = __fmul_rn(__fmul_rn(__fsub_rn(ax1, ax0),
                       __fsub_rn(ay1, ay0)), __fsub_rn(az1, az0));
    const float a1b = __fmul_rn(__fmul_rn(__fsub_rn(bx1, bx0),
                       __fsub_rn(by1, by0)), __fsub_rn(bz1, bz0));
    const float a1c = __fmul_rn(__fmul_rn(__fsub_rn(cx1, cx0),
                       __fsub_rn(cy1, cy0)), __fsub_rn(cz1, cz0));
    const float a1d = __fmul_rn(__fmul_rn(__fsub_rn(dx1, dx0),
                       __fsub_rn(dy1, dy0)), __fsub_rn(dz1, dz0));

    const unsigned encA = 0xFFFFFFFFu - (unsigned)a;
    const unsigned encB = 0xFFFFFFFFu - (unsigned)b;
    const unsigned encC = 0xFFFFFFFFu - (unsigned)c;
    const unsigned encD = 0xFFFFFFFFu - (unsigned)d;

    const int chunk = (M + 3) >> 2;
    const int g0 = wv * chunk;
    const int g1 = (g0 + chunk < M) ? (g0 + chunk) : M;

    float bestA = 0.f, bestB = 0.f, bestC = 0.f, bestD = 0.f;
    int   argA = g0,   argB = g0,   argC = g0,   argD = g0;

    int g = g0;
    for (; g + 3 < g1; g += 4) {
        const float4 glo0 = gb4[2*g+0], ghi0 = gb4[2*g+1];
        const float4 glo1 = gb4[2*g+2], ghi1 = gb4[2*g+3];
        const float4 glo2 = gb4[2*g+4], ghi2 = gb4[2*g+5];
        const float4 glo3 = gb4[2*g+6], ghi3 = gb4[2*g+7];
        IOU_G(glo0, ghi0, g + 0)
        IOU_G(glo1, ghi1, g + 1)
        IOU_G(glo2, ghi2, g + 2)
        IOU_G(glo3, ghi3, g + 3)
    }
    for (; g < g1; ++g) {
        const float4 glo = gb4[2*g], ghi = gb4[2*g+1];
        IOU_G(glo, ghi, g)
    }

    if (va) atomicMax(&asl[0 * 64 + lane],
        ((unsigned long long)__float_as_uint(bestA) << 32) |
        (unsigned long long)(0xFFFFFFFFu - (unsigned)argA));
    if (vb) atomicMax(&asl[1 * 64 + lane],
        ((unsigned long long)__float_as_uint(bestB) << 32) |
        (unsigned long long)(0xFFFFFFFFu - (unsigned)argB));
    if (vc) atomicMax(&asl[2 * 64 + lane],
        ((unsigned long long)__float_as_uint(bestC) << 32) |
        (unsigned long long)(0xFFFFFFFFu - (unsigned)argC));
    if (vd) atomicMax(&asl[3 * 64 + lane],
        ((unsigned long long)__float_as_uint(bestD) << 32) |
        (unsigned long long)(0xFFFFFFFFu - (unsigned)argD));
    __syncthreads();

    if (tid < M) {
        unsigned long long v = lsl[tid];
        if (v) atomicMax(&slots[tid], v);
    }

    {
        const int k = tid >> 6, l = tid & 63;
        const int sb = blockIdx.x * 64 + l;
        const int anchor = sb + k * H;
        if (sb < H && anchor < N) {
            const unsigned long long v = asl[tid];
            const float best = __uint_as_float((unsigned)(v >> 32));
            const int garg = (int)(0xFFFFFFFFu - (unsigned)(v & 0xFFFFFFFFu));
            const float* gbf = (const float*)gb4;
            float lab;
            if (best >= 0.7f) lab = gbf[8 * garg + 7];
            else              lab = (best < 0.3f) ? 0.f : -1.f;
            out_lab[anchor] = lab;
            float* ob = out_bb + (size_t)anchor * 6;
            if (best >= 0.7f) {
                ob[0] = gbf[8*garg+0]; ob[1] = gbf[8*garg+1]; ob[2] = gbf[8*garg+2];
                ob[3] = gbf[8*garg+3]; ob[4] = gbf[8*garg+4]; ob[5] = gbf[8*garg+5];
            } else {
                ob[0] = -1.f; ob[1] = -1.f; ob[2] = -1.f;
                ob[3] = -1.f; ob[4] = -1.f; ob[5] = -1.f;
            }
        }
    }
}

// Low-quality override (separate dispatch — fusing this tail provably makes
// hipcc spill the main loop's live set: R3-R8 ticket, R15 cooperative).
__global__ __launch_bounds__(MMAX) void iou_override(
    const float* __restrict__ gt, const int* __restrict__ gl,
    const unsigned long long* __restrict__ slots,
    float* __restrict__ out_lab, float* __restrict__ out_bb, int M)
{
    __shared__ int s_anchor[MMAX];
    __shared__ int s_cand[MMAX];
    const int i = threadIdx.x;

    int anchor = -1, cand = 0;
    if (i < M) {
        unsigned long long v = slots[i];
        if (v != 0ULL) {               // gt_iou_max >= 0.3 (gated at insert)
            anchor = (int)(0xFFFFFFFFu - (unsigned)(v & 0xFFFFFFFFu));
            cand   = i + 1;
        }
    }
    s_anchor[i] = anchor;
    s_cand[i]   = cand;
    __syncthreads();

    if (cand > 0) {
        bool win = true;
        for (int j = 0; j < M; ++j)
            if (s_cand[j] > cand && s_anchor[j] == anchor) { win = false; break; }
        if (win) {
            out_lab[anchor] = (float)gl[i];
            float* ob = out_bb + (size_t)anchor * 6;
            const float* gp = gt + (size_t)i * 6;
            ob[0] = gp[0]; ob[1] = gp[1]; ob[2] = gp[2];
            ob[3] = gp[3]; ob[4] = gp[4]; ob[5] = gp[5];
        }
    }
}

extern "C" void kernel_launch(void* const* d_in, const int* in_sizes, int n_in,
                              void* d_out, int out_size, void* d_ws, size_t ws_size,
                              hipStream_t stream)
{
    const float* bx = (const float*)d_in[0];
    const float* gt = (const float*)d_in[1];
    const int*   gl = (const int*)d_in[2];
    const int N = in_sizes[0] / 6;
    int M = in_sizes[1] / 6;
    if (M > MMAX) M = MMAX;

    float* out_lab = (float*)d_out;
    float* out_bb  = (float*)d_out + N;

    unsigned long long* slots = (unsigned long long*)d_ws;

    // slots MUST be re-zeroed every call (ws is poisoned once, not re-poisoned
    // between timed replays).
    hipMemsetAsync(d_ws, 0, MMAX * 8, stream);

    if (M == MMAX) {
        const int H8 = (N + 7) / 8;
        const int nblocks = (H8 + 63) / 64;
        hipLaunchKernelGGL(iou_main8, dim3(nblocks), dim3(256), 0, stream,
                           bx, gt, gl, out_lab, out_bb, slots, N);
    } else {
        const int H = (N + 3) / 4;
        const int nblocks = (H + 63) / 64;
        hipLaunchKernelGGL(iou_main_generic, dim3(nblocks), dim3(256), 0, stream,
                           bx, gt, gl, out_lab, out_bb, slots, N, M);
    }
    hipLaunchKernelGGL(iou_override, dim3(1), dim3(MMAX), 0, stream,
                       gt, gl, slots, out_lab, out_bb, M);
}

// Round 18
// 64.372 us; speedup vs baseline: 1.0997x; 1.0997x over previous
//
#include <hip/hip_runtime.h>

// IoU assigner: N anchors x M gts (3D, 6 coords). Outputs (concatenated, f32):
//   out[0:N]   labels (-1 ignore, 0 neg, gt_label pos)
//   out[N:7N]  assigned boxes (gt box if pos, else -1.0)
//
// Bit-exact vs numpy f32: __f*_rn intrinsics (no FMA contraction), op order
// mirrors the jnp reference; argmax ties: first index (strict > scan; the
// cross-chunk merge encodes (iou_bits<<32)|~g so max picks smallest g).
//
// Round-18: R16 (SGPR-delivered gt operands, 4 chains/lane, 43.2us main)
// + ONE change: wave-level __ballot gate around the rare body. Theory: hipcc
// if-converts (speculates) the `inter>0` body's arithmetic -- den + the
// ~12-op full-precision v_div sequence + best/arg cndmasks -- branching only
// around the atomicMax. That doubles the per-pair VALU stream (15->~33 ops),
// exactly explaining the 43us wall at VALUBusy 83% that R12-R17 all hit.
// The __ballot gate (v_cmp + s_cbranch_vccz, no exec save) skips ~80% of
// bodies wholesale (P(any of 64 lanes intersect) ~= 20%), so the speculated
// stream runs only where needed. Bit-exact: same ops on the taken path.
// UNFUSED override + memset (fusion provably spills: R3-R8 ticket, R15 coop).
//
// ws layout: [0,1024) slots[128] u64.

#define MMAX 128

// ---- uniform gt operand load (SMEM s_load via readfirstlane address) ----
#define LOAD_GT(J)                                                             \
    const float q##J##x0 = gq[(J)*6+0], q##J##y0 = gq[(J)*6+1],                \
                q##J##z0 = gq[(J)*6+2], q##J##x1 = gq[(J)*6+3],                \
                q##J##y1 = gq[(J)*6+4], q##J##z1 = gq[(J)*6+5];                \
    const float q##J##ar = __fmul_rn(__fmul_rn(__fsub_rn(q##J##x1, q##J##x0),  \
                            __fsub_rn(q##J##y1, q##J##y0)),                    \
                            __fsub_rn(q##J##z1, q##J##z0));

// ---- one (gt J, chain) IoU step; wave-gated rare body ----
#define IOU_S(J, X0, Y0, Z0, X1, Y1, Z1, AR, BEST, ARG, ENC)                   \
    {                                                                          \
        float cx = fmaxf(__fsub_rn(fminf(X1, q##J##x1), fmaxf(X0, q##J##x0)), 0.f);\
        float cy = fmaxf(__fsub_rn(fminf(Y1, q##J##y1), fmaxf(Y0, q##J##y0)), 0.f);\
        float cz = fmaxf(__fsub_rn(fminf(Z1, q##J##z1), fmaxf(Z0, q##J##z0)), 0.f);\
        float inter = __fmul_rn(__fmul_rn(cx, cy), cz);                        \
        if (__ballot(inter > 0.f)) {   /* wave-cheap: ~80% skip wholesale */   \
            if (inter > 0.f) {                                                 \
                float den = __fadd_rn(__fsub_rn(__fadd_rn(AR, q##J##ar), inter),\
                                      1e-7f);                                  \
                float iou = __fdiv_rn(inter, den);                             \
                if (iou > BEST) { BEST = iou; ARG = u + (J); }                 \
                if (iou >= 0.3f) {                                             \
                    unsigned long long enc =                                   \
                        ((unsigned long long)__float_as_uint(iou) << 32) |     \
                        (unsigned long long)(ENC);                             \
                    atomicMax(&lsl[u + (J)], enc);                             \
                }                                                              \
            }                                                                  \
        }                                                                      \
    }

#define IOU_GT4(J)                                                             \
    IOU_S(J, ax0, ay0, az0, ax1, ay1, az1, a1a, bestA, argA, encA)             \
    IOU_S(J, bx0, by0, bz0, bx1, by1, bz1, a1b, bestB, argB, encB)             \
    IOU_S(J, cx0, cy0, cz0, cx1, cy1, cz1, a1c, bestC, argC, encC)             \
    IOU_S(J, dx0, dy0, dz0, dx1, dy1, dz1, a1d, bestD, argD, encD)

// ---- generic-path macros (R13 verbatim): gt operands from LDS float4 ----
#define IOU_ONE(GLO, GHI, G, X0, Y0, Z0, X1, Y1, Z1, AR, BEST, ARG, ENC)       \
    {                                                                          \
        float cx = fmaxf(__fsub_rn(fminf(X1, GLO.w), fmaxf(X0, GLO.x)), 0.f);  \
        float cy = fmaxf(__fsub_rn(fminf(Y1, GHI.x), fmaxf(Y0, GLO.y)), 0.f);  \
        float cz = fmaxf(__fsub_rn(fminf(Z1, GHI.y), fmaxf(Z0, GLO.z)), 0.f);  \
        float inter = __fmul_rn(__fmul_rn(cx, cy), cz);                        \
        if (__ballot(inter > 0.f)) {                                           \
            if (inter > 0.f) {                                                 \
                float den = __fadd_rn(__fsub_rn(__fadd_rn(AR, GHI.z), inter), 1e-7f);\
                float iou = __fdiv_rn(inter, den);                             \
                if (iou > BEST) { BEST = iou; ARG = (G); }                     \
                if (iou >= 0.3f) {                                             \
                    unsigned long long enc =                                   \
                        ((unsigned long long)__float_as_uint(iou) << 32) |     \
                        (unsigned long long)(ENC);                             \
                    atomicMax(&lsl[(G)], enc);                                 \
                }                                                              \
            }                                                                  \
        }                                                                      \
    }

#define IOU_G(GLO, GHI, G)                                                     \
    IOU_ONE(GLO, GHI, G, ax0, ay0, az0, ax1, ay1, az1, a1a, bestA, argA, encA) \
    IOU_ONE(GLO, GHI, G, bx0, by0, bz0, bx1, by1, bz1, a1b, bestB, argB, encB) \
    IOU_ONE(GLO, GHI, G, cx0, cy0, cz0, cx1, cy1, cz1, a1c, bestC, argC, encC) \
    IOU_ONE(GLO, GHI, G, dx0, dy0, dz0, dx1, dy1, dz1, a1d, bestD, argD, encD)

template <int MC>
__global__ __launch_bounds__(256) void iou_main(
    const float* __restrict__ bx, const float* __restrict__ gt,
    const int* __restrict__ gl,
    float* __restrict__ out_lab, float* __restrict__ out_bb,
    unsigned long long* __restrict__ slots,
    int N, int Mrt)
{
    const int M = MC ? MC : Mrt;
    const int tid  = threadIdx.x;
    const int lane = tid & 63;
    const int wv   = tid >> 6;

    // ---- stage gt tile (epilogue/generic use); zero LDS slots ----
    __shared__ float4 gb4[MMAX * 2];  // [2g]={x0,y0,z0,x1} [2g+1]={y1,z1,area,label}
    __shared__ unsigned long long lsl[MMAX];   // per-gt column max
    __shared__ unsigned long long asl[256];    // per-anchor (best,arg) merge
    if (tid < M) {
        const float* gp = gt + (size_t)tid * 6;
        float x0 = gp[0], y0 = gp[1], z0 = gp[2];
        float x1 = gp[3], y1 = gp[4], z1 = gp[5];
        float area = __fmul_rn(__fmul_rn(__fsub_rn(x1, x0), __fsub_rn(y1, y0)),
                               __fsub_rn(z1, z0));
        gb4[2 * tid]     = make_float4(x0, y0, z0, x1);
        gb4[2 * tid + 1] = make_float4(y1, z1, area, (float)gl[tid]);
    }
    if (tid < MMAX) lsl[tid] = 0ULL;
    asl[tid] = 0ULL;
    __syncthreads();

    // ---- four anchors per LANE at stride H; all 4 waves share them ----
    const int H = (N + 3) >> 2;
    const int base = blockIdx.x * 64 + lane;
    const int a = base, b = base + H, c = base + 2 * H, d = base + 3 * H;
    const bool va = (base < H);
    const bool vb = va && (b < N);
    const bool vc = va && (c < N);
    const bool vd = va && (d < N);

    float ax0 = 0.f, ay0 = 0.f, az0 = 0.f, ax1 = 0.f, ay1 = 0.f, az1 = 0.f;
    if (va) { const float* p = bx + (size_t)a * 6;
        ax0 = p[0]; ay0 = p[1]; az0 = p[2]; ax1 = p[3]; ay1 = p[4]; az1 = p[5]; }
    float bx0 = 0.f, by0 = 0.f, bz0 = 0.f, bx1 = 0.f, by1 = 0.f, bz1 = 0.f;
    if (vb) { const float* p = bx + (size_t)b * 6;
        bx0 = p[0]; by0 = p[1]; bz0 = p[2]; bx1 = p[3]; by1 = p[4]; bz1 = p[5]; }
    float cx0 = 0.f, cy0 = 0.f, cz0 = 0.f, cx1 = 0.f, cy1 = 0.f, cz1 = 0.f;
    if (vc) { const float* p = bx + (size_t)c * 6;
        cx0 = p[0]; cy0 = p[1]; cz0 = p[2]; cx1 = p[3]; cy1 = p[4]; cz1 = p[5]; }
    float dx0 = 0.f, dy0 = 0.f, dz0 = 0.f, dx1 = 0.f, dy1 = 0.f, dz1 = 0.f;
    if (vd) { const float* p = bx + (size_t)d * 6;
        dx0 = p[0]; dy0 = p[1]; dz0 = p[2]; dx1 = p[3]; dy1 = p[4]; dz1 = p[5]; }

    const float a1a = __fmul_rn(__fmul_rn(__fsub_rn(ax1, ax0),
                       __fsub_rn(ay1, ay0)), __fsub_rn(az1, az0));
    const float a1b = __fmul_rn(__fmul_rn(__fsub_rn(bx1, bx0),
                       __fsub_rn(by1, by0)), __fsub_rn(bz1, bz0));
    const float a1c = __fmul_rn(__fmul_rn(__fsub_rn(cx1, cx0),
                       __fsub_rn(cy1, cy0)), __fsub_rn(cz1, cz0));
    const float a1d = __fmul_rn(__fmul_rn(__fsub_rn(dx1, dx0),
                       __fsub_rn(dy1, dy0)), __fsub_rn(dz1, dz0));

    const unsigned encA = 0xFFFFFFFFu - (unsigned)a;   // loop-invariant
    const unsigned encB = 0xFFFFFFFFu - (unsigned)b;
    const unsigned encC = 0xFFFFFFFFu - (unsigned)c;
    const unsigned encD = 0xFFFFFFFFu - (unsigned)d;

    const int chunk = (M + 3) >> 2;
    const int g0w = wv * chunk;

    float bestA = 0.f, bestB = 0.f, bestC = 0.f, bestD = 0.f;
    int   argA = g0w,  argB = g0w,  argC = g0w,  argD = g0w;

    if constexpr (MC == MMAX) {
        // ---- fast path: 4 sub-chunks of 8 gts; 48 uniform floats preloaded
        //      via readfirstlane-uniform address (-> SMEM s_load), then 32
        //      wave-gated IoU instances per sub-chunk ----
        for (int cs = 0; cs < 32; cs += 8) {
            const int u = __builtin_amdgcn_readfirstlane(g0w + cs);
            const float* gq = gt + (size_t)u * 6;
            LOAD_GT(0) LOAD_GT(1) LOAD_GT(2) LOAD_GT(3)
            LOAD_GT(4) LOAD_GT(5) LOAD_GT(6) LOAD_GT(7)
            IOU_GT4(0) IOU_GT4(1) IOU_GT4(2) IOU_GT4(3)
            IOU_GT4(4) IOU_GT4(5) IOU_GT4(6) IOU_GT4(7)
        }
    } else {
        // ---- generic path (runtime M): LDS loop ----
        const int u = 0; (void)u;
        const int g1 = (g0w + chunk < M) ? (g0w + chunk) : M;
        int g = g0w;
        for (; g + 3 < g1; g += 4) {
            const float4 glo0 = gb4[2*g+0], ghi0 = gb4[2*g+1];
            const float4 glo1 = gb4[2*g+2], ghi1 = gb4[2*g+3];
            const float4 glo2 = gb4[2*g+4], ghi2 = gb4[2*g+5];
            const float4 glo3 = gb4[2*g+6], ghi3 = gb4[2*g+7];
            IOU_G(glo0, ghi0, g + 0)
            IOU_G(glo1, ghi1, g + 1)
            IOU_G(glo2, ghi2, g + 2)
            IOU_G(glo3, ghi3, g + 3)
        }
        for (; g < g1; ++g) {
            const float4 glo = gb4[2*g], ghi = gb4[2*g+1];
            IOU_G(glo, ghi, g)
        }
    }

    // ---- merge per-anchor chunk results: (iou_bits<<32)|~g, max = best iou,
    //      smallest g on ties (first-index argmax across the full 0..M-1) ----
    if (va) atomicMax(&asl[0 * 64 + lane],
        ((unsigned long long)__float_as_uint(bestA) << 32) |
        (unsigned long long)(0xFFFFFFFFu - (unsigned)argA));
    if (vb) atomicMax(&asl[1 * 64 + lane],
        ((unsigned long long)__float_as_uint(bestB) << 32) |
        (unsigned long long)(0xFFFFFFFFu - (unsigned)argB));
    if (vc) atomicMax(&asl[2 * 64 + lane],
        ((unsigned long long)__float_as_uint(bestC) << 32) |
        (unsigned long long)(0xFFFFFFFFu - (unsigned)argC));
    if (vd) atomicMax(&asl[3 * 64 + lane],
        ((unsigned long long)__float_as_uint(bestD) << 32) |
        (unsigned long long)(0xFFFFFFFFu - (unsigned)argD));
    __syncthreads();

    // ---- flush per-gt maxima to global slots ----
    if (tid < M) {
        unsigned long long v = lsl[tid];
        if (v) atomicMax(&slots[tid], v);
    }

    // ---- epilogue: threads own the 256 anchor slots ----
    {
        const int k = tid >> 6, l = tid & 63;
        const int sb = blockIdx.x * 64 + l;
        const int anchor = sb + k * H;
        if (sb < H && anchor < N) {
            const unsigned long long v = asl[tid];
            const float best = __uint_as_float((unsigned)(v >> 32));
            const int garg = (int)(0xFFFFFFFFu - (unsigned)(v & 0xFFFFFFFFu));
            const float* gbf = (const float*)gb4;   // [8g+0..5]=box +6=area +7=label
            float lab;
            if (best >= 0.7f) lab = gbf[8 * garg + 7];
            else              lab = (best < 0.3f) ? 0.f : -1.f;
            out_lab[anchor] = lab;
            float* ob = out_bb + (size_t)anchor * 6;
            if (best >= 0.7f) {
                ob[0] = gbf[8*garg+0]; ob[1] = gbf[8*garg+1]; ob[2] = gbf[8*garg+2];
                ob[3] = gbf[8*garg+3]; ob[4] = gbf[8*garg+4]; ob[5] = gbf[8*garg+5];
            } else {
                ob[0] = -1.f; ob[1] = -1.f; ob[2] = -1.f;
                ob[3] = -1.f; ob[4] = -1.f; ob[5] = -1.f;
            }
        }
    }
}

// Low-quality override (separate dispatch — fusing this tail provably makes
// hipcc spill the main loop's live set: R3-R8 ticket, R15 cooperative): for
// each gt with a nonzero slot (column max >= 0.3), its argmax anchor gets
// that gt; when several gts pick the same anchor the LARGEST gt index wins
// (mirrors the reference's .at[].max scatter).
__global__ __launch_bounds__(MMAX) void iou_override(
    const float* __restrict__ gt, const int* __restrict__ gl,
    const unsigned long long* __restrict__ slots,
    float* __restrict__ out_lab, float* __restrict__ out_bb, int M)
{
    __shared__ int s_anchor[MMAX];
    __shared__ int s_cand[MMAX];
    const int i = threadIdx.x;

    int anchor = -1, cand = 0;
    if (i < M) {
        unsigned long long v = slots[i];
        if (v != 0ULL) {               // gt_iou_max >= 0.3 (gated at insert)
            anchor = (int)(0xFFFFFFFFu - (unsigned)(v & 0xFFFFFFFFu));
            cand   = i + 1;
        }
    }
    s_anchor[i] = anchor;
    s_cand[i]   = cand;
    __syncthreads();

    if (cand > 0) {
        bool win = true;
        for (int j = 0; j < M; ++j)
            if (s_cand[j] > cand && s_anchor[j] == anchor) { win = false; break; }
        if (win) {
            out_lab[anchor] = (float)gl[i];
            float* ob = out_bb + (size_t)anchor * 6;
            const float* gp = gt + (size_t)i * 6;
            ob[0] = gp[0]; ob[1] = gp[1]; ob[2] = gp[2];
            ob[3] = gp[3]; ob[4] = gp[4]; ob[5] = gp[5];
        }
    }
}

extern "C" void kernel_launch(void* const* d_in, const int* in_sizes, int n_in,
                              void* d_out, int out_size, void* d_ws, size_t ws_size,
                              hipStream_t stream)
{
    const float* bx = (const float*)d_in[0];
    const float* gt = (const float*)d_in[1];
    const int*   gl = (const int*)d_in[2];
    const int N = in_sizes[0] / 6;
    int M = in_sizes[1] / 6;
    if (M > MMAX) M = MMAX;

    float* out_lab = (float*)d_out;
    float* out_bb  = (float*)d_out + N;

    unsigned long long* slots = (unsigned long long*)d_ws;

    // slots MUST be re-zeroed every call (ws is poisoned once, not re-poisoned
    // between timed replays).
    hipMemsetAsync(d_ws, 0, MMAX * 8, stream);

    const int H = (N + 3) / 4;
    const int nblocks = (H + 63) / 64;

    if (M == MMAX) {
        hipLaunchKernelGGL(iou_main<MMAX>, dim3(nblocks), dim3(256), 0, stream,
                           bx, gt, gl, out_lab, out_bb, slots, N, M);
    } else {
        hipLaunchKernelGGL(iou_main<0>, dim3(nblocks), dim3(256), 0, stream,
                           bx, gt, gl, out_lab, out_bb, slots, N, M);
    }
    hipLaunchKernelGGL(iou_override, dim3(1), dim3(MMAX), 0, stream,
                       gt, gl, slots, out_lab, out_bb, M);
}